// Round 1
// baseline (393.936 us; speedup 1.0000x reference)
//
#include <hip/hip_runtime.h>
#include <cmath>

namespace {

constexpr int Bsz = 8, NC = 10, BC = 80, S = 512, H = 768, G4 = 3072, H2 = 1536;
constexpr int NSP = 8;         // s-chunks for weighted partial sums
constexpr int SCH = S / NSP;   // 64

__device__ __forceinline__ float sigm(float x){ return 1.0f/(1.0f + __expf(-x)); }
// tanh via exp, safe at +-inf: 1 - 2/(e^{2x}+1)
__device__ __forceinline__ float tanh_fast(float x){ return 1.0f - 2.0f/(__expf(2.0f*x) + 1.0f); }

__device__ __forceinline__ float wred(float v){
  #pragma unroll
  for (int m = 32; m; m >>= 1) v += __shfl_xor(v, m, 64);
  return v;
}
__device__ __forceinline__ float dot4(float4 a, float4 b){
  return a.x*b.x + a.y*b.y + a.z*b.z + a.w*b.w;
}

// ---- 1. scores[bc][s] = sigmoid(dot(tok[bc,s,:], w_tok) + b_tok) ----
// one wave per (bc,s); grid = BC*S/4 blocks of 256
__global__ void k_scores(const float* __restrict__ tok, const float* __restrict__ w_tok,
                         const float* __restrict__ b_tok, float* __restrict__ scores){
  int wid  = (int)((blockIdx.x * blockDim.x + threadIdx.x) >> 6);  // == bc*S+s
  int lane = threadIdx.x & 63;
  const float4* t4 = (const float4*)(tok + (size_t)wid * H);
  const float4* w4 = (const float4*)w_tok;
  float acc = 0.f;
  #pragma unroll
  for (int k = 0; k < 3; k++) acc += dot4(t4[lane + k*64], w4[lane + k*64]);
  acc = wred(acc);
  if (lane == 0) scores[wid] = sigm(acc + b_tok[0]);
}

// ---- 2. windowed (5-tap centered avg, zero padded, always /5) -> d_out ----
__global__ void k_windowed(const float* __restrict__ scores, float* __restrict__ out_win){
  int idx = blockIdx.x * blockDim.x + threadIdx.x;
  if (idx >= BC * S) return;
  int s = idx & (S - 1);
  const float* row = scores + (idx - s);
  float acc = 0.f;
  #pragma unroll
  for (int d = -2; d <= 2; d++){
    int ss = s + d;
    if (ss >= 0 && ss < S) acc += row[ss];
  }
  out_win[idx] = acc * 0.2f;
}

// ---- 3. weighted partials: wpart[ch][bc][h] = sum_{s in chunk} tok*win ----
// grid = BC*NSP blocks of 192 (each thread owns one float4 column)
__global__ void k_weighted(const float* __restrict__ tok, const float* __restrict__ win,
                           float* __restrict__ wpart){
  int bc = blockIdx.x >> 3, ch = blockIdx.x & 7;
  int tid = threadIdx.x;  // 0..191
  __shared__ float wsh[SCH];
  int s0 = ch * SCH;
  if (tid < SCH) wsh[tid] = win[(size_t)bc * S + s0 + tid];
  __syncthreads();
  const float4* base = (const float4*)(tok + ((size_t)bc * S + s0) * H) + tid;
  float4 acc = {0.f, 0.f, 0.f, 0.f};
  #pragma unroll 4
  for (int s = 0; s < SCH; s++){
    float w = wsh[s];
    float4 a = base[(size_t)s * (H/4)];
    acc.x += a.x * w; acc.y += a.y * w; acc.z += a.z * w; acc.w += a.w * w;
  }
  ((float4*)(wpart + ((size_t)(ch * BC + bc)) * H))[tid] = acc;
}

// ---- 4. wmean[b][h] = mean over chunks (and partials) ----
__global__ void k_wmean(const float* __restrict__ wpart, float* __restrict__ wmean){
  int idx = blockIdx.x * blockDim.x + threadIdx.x;
  if (idx >= Bsz * H) return;
  int b = idx / H, h = idx - b * H;
  float acc = 0.f;
  for (int p = 0; p < NSP; p++)
    #pragma unroll
    for (int c = 0; c < NC; c++)
      acc += wpart[((size_t)(p * BC + b * NC + c)) * H + h];
  wmean[idx] = acc * 0.1f;
}

// ---- small row-GEMM: out[b][o] = dot(A[b,:H], W[o,:H]) + bias[o] ----
// one wave per o, loops over NB batch rows
template<int NB>
__global__ void k_gemm_bt(const float* __restrict__ A, const float* __restrict__ W,
                          const float* __restrict__ bias, float* __restrict__ Cout, int no){
  int o = (int)((blockIdx.x * blockDim.x + threadIdx.x) >> 6);
  int lane = threadIdx.x & 63;
  if (o >= no) return;
  const float4* w4 = (const float4*)(W + (size_t)o * H);
  float4 w0 = w4[lane], w1 = w4[lane+64], w2 = w4[lane+128];
  float bb = bias[o];
  #pragma unroll
  for (int b = 0; b < NB; b++){
    const float4* a4 = (const float4*)(A + (size_t)b * H);
    float acc = dot4(a4[lane], w0) + dot4(a4[lane+64], w1) + dot4(a4[lane+128], w2);
    acc = wred(acc);
    if (lane == 0) Cout[(size_t)b * no + o] = acc + bb;
  }
}

// ---- x-part LSTM gates: outg[i][g] = dot(tok[(i*mul+add)*S + 0, :], w[g]) + bih[g]+bhh[g] ----
__global__ void k_xgate(const float* __restrict__ tok, const float* __restrict__ w,
                        const float* __restrict__ bih, const float* __restrict__ bhh,
                        float* __restrict__ outg, int nb, int mul, int add){
  int g = (int)((blockIdx.x * blockDim.x + threadIdx.x) >> 6);
  int lane = threadIdx.x & 63;
  if (g >= G4) return;
  const float4* w4 = (const float4*)(w + (size_t)g * H);
  float4 w0 = w4[lane], w1 = w4[lane+64], w2 = w4[lane+128];
  float bb = bih[g] + bhh[g];
  for (int i = 0; i < nb; i++){
    size_t bc = (size_t)(i * mul + add);
    const float4* a4 = (const float4*)(tok + bc * (size_t)S * H);
    float acc = dot4(a4[lane], w0) + dot4(a4[lane+64], w1) + dot4(a4[lane+128], w2);
    acc = wred(acc);
    if (lane == 0) outg[(size_t)i * G4 + g] = acc + bb;
  }
}

// ---- one LSTM forward step ----
// phase A (redundant per block): (h_t, c_t) from gates[t-1] (gprev) and c[t-1] (cprev),
//   h_t -> LDS; block 0 persists c_t -> ccur.
// phase B: gcur[b][r] = xg[(b*NC+t)][r] + dot(h_t[b,:], w_hh[r,:])
// grid = 192 blocks of 256 (16 rows per block, 4 per wave)
__global__ void k_step(const float* __restrict__ w_hh, const float* __restrict__ xg,
                       const float* __restrict__ gprev, const float* __restrict__ cprev,
                       float* __restrict__ gcur, float* __restrict__ ccur, int t){
  __shared__ float hsh[Bsz * H];
  int tid = threadIdx.x;
  if (t == 0){
    for (int i = tid; i < Bsz * H; i += 256){
      hsh[i] = 0.f;
      if (blockIdx.x == 0) ccur[i] = 0.f;
    }
  } else {
    for (int i = tid; i < Bsz * H; i += 256){
      int b = i / H, j = i - b * H;
      const float* gp = gprev + (size_t)b * G4 + j;
      float ig = gp[0], fg = gp[H], gg = gp[2*H], og = gp[3*H];
      float c = sigm(fg) * cprev[i] + sigm(ig) * tanh_fast(gg);
      float h = sigm(og) * tanh_fast(c);
      hsh[i] = h;
      if (blockIdx.x == 0) ccur[i] = c;
    }
  }
  __syncthreads();
  int lane = tid & 63, wv = tid >> 6;
  int r0 = blockIdx.x * 16 + wv * 4;
  #pragma unroll
  for (int rr = 0; rr < 4; rr++){
    int r = r0 + rr;
    const float4* w4 = (const float4*)(w_hh + (size_t)r * H);
    float4 w0 = w4[lane], w1 = w4[lane+64], w2 = w4[lane+128];
    #pragma unroll
    for (int b = 0; b < Bsz; b++){
      const float4* h4 = (const float4*)(hsh + b * H);
      float acc = dot4(h4[lane], w0) + dot4(h4[lane+64], w1) + dot4(h4[lane+128], w2);
      acc = wred(acc);
      if (lane == 0) gcur[(size_t)b * G4 + r] = acc + xg[(size_t)(b * NC + t) * G4 + r];
    }
  }
}

// ---- final LSTM updates: h10 (fwd) and one backward step -> glob[b][0:1536] ----
__global__ void k_fin1(const float* __restrict__ g9, const float* __restrict__ c9,
                       const float* __restrict__ gb, float* __restrict__ glob){
  int i = blockIdx.x * blockDim.x + threadIdx.x;
  if (i >= Bsz * H) return;
  int b = i / H, j = i - b * H;
  const float* gp = g9 + (size_t)b * G4 + j;
  float c10 = sigm(gp[H]) * c9[i] + sigm(gp[0]) * tanh_fast(gp[2*H]);
  float h10 = sigm(gp[3*H]) * tanh_fast(c10);
  const float* gq = gb + (size_t)b * G4 + j;
  float cb = sigm(gq[0]) * tanh_fast(gq[2*H]);   // c_prev = 0 for backward's first step
  float hb = sigm(gq[3*H]) * tanh_fast(cb);
  glob[(size_t)b * H2 + j]     = h10;
  glob[(size_t)b * H2 + H + j] = hb;
}

// ---- class head: sigmoid(dot(glob[b]+summ[b], w_cls) + b_cls) ----
__global__ void k_cls(const float* __restrict__ glob, const float* __restrict__ summ,
                      const float* __restrict__ w_cls, const float* __restrict__ b_cls,
                      float* __restrict__ cls){
  int tid = threadIdx.x;
  int b = tid >> 6, lane = tid & 63;
  const float4* g4 = (const float4*)(glob + (size_t)b * H2);
  const float4* s4 = (const float4*)(summ + (size_t)b * H2);
  const float4* w4 = (const float4*)w_cls;
  float acc = 0.f;
  #pragma unroll
  for (int k = 0; k < 6; k++){
    float4 g = g4[lane + k*64], s = s4[lane + k*64], w = w4[lane + k*64];
    acc += (g.x+s.x)*w.x + (g.y+s.y)*w.y + (g.z+s.z)*w.z + (g.w+s.w)*w.w;
  }
  acc = wred(acc);
  if (lane == 0) cls[b] = sigm(acc + b_cls[0]);
}

} // namespace

extern "C" void kernel_launch(void* const* d_in, const int* in_sizes, int n_in,
                              void* d_out, int out_size, void* d_ws, size_t ws_size,
                              hipStream_t stream) {
  const float* tok    = (const float*)d_in[0];
  const float* w_tok  = (const float*)d_in[1];
  const float* b_tok  = (const float*)d_in[2];
  const float* w_sum  = (const float*)d_in[3];
  const float* b_sum  = (const float*)d_in[4];
  const float* w_proj = (const float*)d_in[5];
  const float* b_proj = (const float*)d_in[6];
  const float* w_ih_f = (const float*)d_in[7];
  const float* w_hh_f = (const float*)d_in[8];
  const float* b_ih_f = (const float*)d_in[9];
  const float* b_hh_f = (const float*)d_in[10];
  const float* w_ih_b = (const float*)d_in[11];
  const float* w_hh_b = (const float*)d_in[12];  (void)w_hh_b; // backward uses only 1 step from h=0
  const float* b_ih_b = (const float*)d_in[13];
  const float* b_hh_b = (const float*)d_in[14];
  const float* w_cls  = (const float*)d_in[15];
  const float* b_cls  = (const float*)d_in[16];

  float* out      = (float*)d_out;
  float* cls_out  = out;                 // 8
  float* win_out  = out + 8;             // 40960
  float* summ_out = out + 8 + BC * S;    // 12288

  float* ws     = (float*)d_ws;
  float* scores = ws;                    // 40960
  float* wpart  = scores + BC * S;       // NSP*BC*H = 491520
  float* wmean  = wpart + NSP * BC * H;  // 6144
  float* s1     = wmean + Bsz * H;       // 6144
  float* xg     = s1 + Bsz * H;          // 245760
  float* gb     = xg + (size_t)BC * G4;  // 24576
  float* gA     = gb + Bsz * G4;         // 24576
  float* gB     = gA + Bsz * G4;         // 24576
  float* cA     = gB + Bsz * G4;         // 6144
  float* cB     = cA + Bsz * H;          // 6144
  float* glob   = cB + Bsz * H;          // 12288

  // windowed-summary path
  k_scores<<<BC * S / 4, 256, 0, stream>>>(tok, w_tok, b_tok, scores);
  k_windowed<<<(BC * S + 255) / 256, 256, 0, stream>>>(scores, win_out);
  k_weighted<<<BC * NSP, 192, 0, stream>>>(tok, win_out, wpart);
  k_wmean<<<(Bsz * H + 255) / 256, 256, 0, stream>>>(wpart, wmean);
  k_gemm_bt<Bsz><<<(H * 64) / 256, 256, 0, stream>>>(wmean, w_sum, b_sum, s1, H);
  k_gemm_bt<Bsz><<<(H2 * 64) / 256, 256, 0, stream>>>(s1, w_proj, b_proj, summ_out, H2);

  // LSTM x-gates (fwd: all 80 (b,t); bwd: only t=9 rows, single step needed)
  k_xgate<<<(G4 * 64) / 256, 256, 0, stream>>>(tok, w_ih_f, b_ih_f, b_hh_f, xg, BC, 1, 0);
  k_xgate<<<(G4 * 64) / 256, 256, 0, stream>>>(tok, w_ih_b, b_ih_b, b_hh_b, gb, Bsz, NC, NC - 1);

  // 10 sequential forward steps (double-buffered gates/c)
  for (int t = 0; t < NC; t++){
    float* gcur  = (t & 1) ? gB : gA;
    float* gprev = (t & 1) ? gA : gB;
    float* ccur  = (t & 1) ? cB : cA;
    float* cprev = (t & 1) ? cA : cB;
    k_step<<<192, 256, 0, stream>>>(w_hh_f, xg, gprev, cprev, gcur, ccur, t);
  }
  // after t=9 (odd): gates[9] in gB, c[9] in cB
  k_fin1<<<(Bsz * H + 255) / 256, 256, 0, stream>>>(gB, cB, gb, glob);
  k_cls<<<1, 512, 0, stream>>>(glob, summ_out, w_cls, b_cls, cls_out);
}